// Round 10
// baseline (203.203 us; speedup 1.0000x reference)
//
#include <hip/hip_runtime.h>
#include <math.h>

// Problem constants
#define BB 4
#define CIN 64
#define COUT 64
#define HH 128
#define WW 128
#define HW (HH*WW)

typedef __attribute__((ext_vector_type(8))) short short8;   // 8 bf16 = 4 VGPRs
typedef __attribute__((ext_vector_type(4))) float f32x4;
typedef __attribute__((ext_vector_type(4))) unsigned int uint4v;

static __device__ __forceinline__ unsigned short f2bf(float f) {
    unsigned int u = __builtin_bit_cast(unsigned int, f);
    u += 0x7fffu + ((u >> 16) & 1u);          // round-to-nearest-even
    return (unsigned short)(u >> 16);
}
static __device__ __forceinline__ float bf2f(unsigned short h) {
    unsigned int u = ((unsigned int)h) << 16;
    return __builtin_bit_cast(float, u);
}

// ---------------------------------------------------------------------------
// shared bodies
// ---------------------------------------------------------------------------
// channel-last bf16 transpose of one (b, 64-px strip): src[b][c][px] -> dst[b][px][c]
static __device__ __forceinline__ void transpose_body(
        const float* __restrict__ srcb, unsigned short* __restrict__ dstb,
        int tb, int tid, float* lt /* 64*65 floats */) {
    int b = tb >> 8;
    int px0 = (tb & 255) * 64;
    const float* src = srcb + (size_t)b*CIN*HW + px0;
    for (int i = tid; i < 4096; i += 256) {
        int c = i >> 6, px = i & 63;
        lt[c*65 + px] = src[(size_t)c*HW + px];
    }
    __syncthreads();
    int q = tid & 3, px = tid >> 2;     // px 0..63, q = 16-ch quarter
    unsigned short* dst = dstb + ((size_t)b*HW + px0 + px)*64 + q*16;
    #pragma unroll
    for (int s = 0; s < 2; ++s) {
        short8 pk;
        #pragma unroll
        for (int j = 0; j < 8; ++j)
            pk[j] = (short)f2bf(lt[(q*16 + s*8 + j)*65 + px]);
        *(short8*)(dst + s*8) = pk;
    }
}

static __device__ __forceinline__ void fvec_body(
        int tid, const float* __restrict__ c1w, const float* __restrict__ fea,
        const float* __restrict__ c2w, const float* __restrict__ bias,
        float* __restrict__ fvec, float* __restrict__ bias2) {
    int b = tid >> 6, c = tid & 63;
    float s = 0.f;
    for (int i = 0; i < 4*CIN; ++i) s += c1w[c*(4*CIN) + i] * fea[b*(4*CIN) + i];
    fvec[tid] = s;
    if (tid < COUT) {
        float s2 = 0.f;
        for (int o = 0; o < COUT; ++o) s2 += c2w[tid*COUT + o] * bias[o];
        bias2[tid] = s2;
    }
}

static __device__ __forceinline__ void wkpack_body(
        int i, const float* __restrict__ com_w, unsigned short* __restrict__ wk2) {
    int k = i & 31, oc = (i >> 5) & 31;
    int cc5 = i >> 10;                  // cg*5 + chunk
    int cg = cc5 / 5, ch = cc5 % 5;
    int tap = ch*2 + (k >> 4);
    int c = cg*16 + (k & 15);
    float v = 0.f;
    if (tap < 9 && oc < 27) v = com_w[((size_t)oc*64 + c)*9 + tap];
    wk2[i] = f2bf(v);
}

// W2b[b][p][o2][c] bf16 (MFMA A layout)
static __device__ __forceinline__ void w2_body(
        int wid, int tid, const float* __restrict__ weight,
        const float* __restrict__ c2w, const float* __restrict__ fvec,
        unsigned short* __restrict__ w2b, float* c2s, float* wcol) {
    int o2 = tid & 63, ci = tid >> 6;
    int bp = wid >> 4;
    int c_base = (wid & 15)*4;
    int p = bp % 9, b = bp / 9;
    int c = c_base + ci;
    for (int idx = tid; idx < 4096; idx += 256) {
        int o2r = idx >> 6, oc = idx & 63;
        c2s[oc*65 + o2r] = c2w[idx];
    }
    {
        int o = tid & 63, cw = tid >> 6;
        wcol[cw*64 + o] = weight[(o*CIN + (c_base + cw))*9 + p];
    }
    __syncthreads();
    float s = 0.f;
    #pragma unroll 8
    for (int o = 0; o < COUT; ++o) s += c2s[o*65 + o2] * wcol[ci*64 + o];
    w2b[(size_t)bp*4096 + o2*64 + c] = f2bf(s * fvec[b*CIN + c]);
}

// conv via register MFMA from channel-last iT (no LDS)
static __device__ __forceinline__ void conv_fast_body(
        int id, int tid, const unsigned short* __restrict__ iT,
        const unsigned short* __restrict__ wk2, const float* __restrict__ com_b,
        float* __restrict__ om) {
    const int KYE[5] = {0,0,1,2,2}, KXE[5] = {0,2,1,0,2};
    const int KYO[5] = {0,1,1,2,0}, KXO[5] = {1,0,2,1,0};
    int bz = id >> 6;                 // b*2 + mh
    int b = bz >> 1, mh = bz & 1;
    int by = (id >> 3) & 7, bx = id & 7;
    int x0 = bx*16, y0 = by*16;
    int lane = tid & 63, wv = tid >> 6;
    int nn = lane & 15, qq = lane >> 4;
    int qq1 = qq >> 1, qh = qq & 1;
    const unsigned short* iTb = iT + (size_t)b*HW*64;

    f32x4 acc[4];
    #pragma unroll
    for (int nt = 0; nt < 4; ++nt)
        #pragma unroll
        for (int j = 0; j < 4; ++j) acc[nt][j] = 0.f;

    #pragma unroll
    for (int cg = 0; cg < 4; ++cg) {
        short8 afr[5];
        #pragma unroll
        for (int ch = 0; ch < 5; ++ch)
            afr[ch] = *(const short8*)(wk2 +
                (((size_t)(cg*5 + ch)*32 + mh*16 + nn)*32 + qq*8));
        #pragma unroll
        for (int ch = 0; ch < 5; ++ch) {
            int ky = qq1 ? KYO[ch] : KYE[ch];
            int kx = qq1 ? KXO[ch] : KXE[ch];
            bool tv = !(ch == 4 && qq1);
            int gx = x0 + nn + kx - 1;
            bool vx = tv && (gx >= 0) && (gx < WW);
            #pragma unroll
            for (int nt = 0; nt < 4; ++nt) {
                int gy = y0 + wv*4 + nt + ky - 1;
                bool ok = vx && (gy >= 0) && (gy < HH);
                short8 bv = {0,0,0,0,0,0,0,0};
                if (ok) bv = *(const short8*)(iTb +
                                (size_t)(gy*WW + gx)*64 + cg*16 + qh*8);
                acc[nt] = __builtin_amdgcn_mfma_f32_16x16x32_bf16(
                              afr[ch], bv, acc[nt], 0, 0, 0);
            }
        }
    }

    float* op = om + (size_t)b*27*HW;
    #pragma unroll
    for (int nt = 0; nt < 4; ++nt) {
        int pix = (y0 + wv*4 + nt)*WW + x0 + nn;
        #pragma unroll
        for (int j = 0; j < 4; ++j) {
            int oc = mh*16 + qq*4 + j;
            if (oc < 27)
                op[(size_t)oc*HW + pix] = acc[nt][j] + com_b[oc];
        }
    }
}

// conv via LDS im2col tile (fallback when ws has no room for iT)
static __device__ __forceinline__ void conv_lds_body(
        int id, int tid, const float* __restrict__ inter,
        const unsigned short* __restrict__ wk2, const float* __restrict__ com_b,
        float* __restrict__ om, float* smemf) {
    unsigned short* til = (unsigned short*)smemf;   // [325][24]
    int bz = id >> 6;
    int b = bz >> 1, mh = bz & 1;
    int by = (id >> 3) & 7, bx = id & 7;
    int x0 = bx*16, y0 = by*16;
    int lane = tid & 63, wv = tid >> 6;
    int nn = lane & 15, qq = lane >> 4;

    f32x4 acc[4];
    #pragma unroll
    for (int nt = 0; nt < 4; ++nt)
        #pragma unroll
        for (int j = 0; j < 4; ++j) acc[nt][j] = 0.f;

    for (int cg = 0; cg < 4; ++cg) {
        __syncthreads();
        const float* I = inter + ((size_t)(b*CIN + cg*16))*HW;
        for (int i = tid; i < 16*324; i += 256) {
            int cl = i / 324, px = i % 324;
            int r = px / 18, cc = px % 18;
            int gy = y0 + r - 1, gx = x0 + cc - 1;
            float v = 0.f;
            if (gy >= 0 && gy < HH && gx >= 0 && gx < WW)
                v = I[(size_t)cl*HW + gy*WW + gx];
            til[px*24 + cl] = f2bf(v);
        }
        if (tid < 24) til[324*24 + tid] = 0;
        __syncthreads();

        short8 afr[5];
        #pragma unroll
        for (int ch = 0; ch < 5; ++ch)
            afr[ch] = *(const short8*)(wk2 +
                (((size_t)(cg*5 + ch)*32 + mh*16 + nn)*32 + qq*8));
        #pragma unroll
        for (int nt = 0; nt < 4; ++nt) {
            int row = wv*4 + nt;
            #pragma unroll
            for (int ch = 0; ch < 5; ++ch) {
                int tap = ch*2 + (qq >> 1);
                int px_idx;
                if (tap > 8) px_idx = 324;
                else {
                    int ky = tap/3, kx = tap%3;
                    px_idx = (row + ky)*18 + (nn + kx);
                }
                short8 bfr = *(const short8*)(til + px_idx*24 + (qq&1)*8);
                acc[nt] = __builtin_amdgcn_mfma_f32_16x16x32_bf16(
                              afr[ch], bfr, acc[nt], 0, 0, 0);
            }
        }
    }

    float* op = om + (size_t)b*27*HW;
    #pragma unroll
    for (int nt = 0; nt < 4; ++nt) {
        int pix = (y0 + wv*4 + nt)*WW + x0 + nn;
        #pragma unroll
        for (int j = 0; j < 4; ++j) {
            int oc = mh*16 + qq*4 + j;
            if (oc < 27)
                op[(size_t)oc*HW + pix] = acc[nt][j] + com_b[oc];
        }
    }
}

// ---------------------------------------------------------------------------
// K1-big: iT transpose (1024) + fvec/bias2 (1) + wkpack (80) = 1105 blocks
// ---------------------------------------------------------------------------
__global__ __launch_bounds__(256) void prep_big_kernel(
        const float* __restrict__ inter,
        const float* __restrict__ c1w, const float* __restrict__ fea,
        const float* __restrict__ c2w, const float* __restrict__ bias,
        const float* __restrict__ com_w,
        unsigned short* __restrict__ iT, float* __restrict__ fvec,
        float* __restrict__ bias2, unsigned short* __restrict__ wk2) {
    __shared__ float smem[64*65];
    int id = blockIdx.x, tid = threadIdx.x;
    if (id < 1024)       transpose_body(inter, iT, id, tid, smem);
    else if (id == 1024) fvec_body(tid, c1w, fea, c2w, bias, fvec, bias2);
    else                 wkpack_body((id - 1025)*256 + tid, com_w, wk2);
}

// K1-small: fvec (1) + wkpack (80) = 81 blocks
__global__ __launch_bounds__(256) void prep_small_kernel(
        const float* __restrict__ c1w, const float* __restrict__ fea,
        const float* __restrict__ c2w, const float* __restrict__ bias,
        const float* __restrict__ com_w,
        float* __restrict__ fvec, float* __restrict__ bias2,
        unsigned short* __restrict__ wk2) {
    int id = blockIdx.x, tid = threadIdx.x;
    if (id == 0) fvec_body(tid, c1w, fea, c2w, bias, fvec, bias2);
    else         wkpack_body((id - 1)*256 + tid, com_w, wk2);
}

// ---------------------------------------------------------------------------
// K2-big: conv_fast (512) + w2 (576) + fT transpose (1024) = 2112 blocks
//         fT transpose runs concurrently with conv (no dependency).
// ---------------------------------------------------------------------------
__global__ __launch_bounds__(256) void main2_big_kernel(
        const float* __restrict__ input_feat,
        const unsigned short* __restrict__ iT,
        const unsigned short* __restrict__ wk2,
        const float* __restrict__ com_b,
        const float* __restrict__ weight,
        const float* __restrict__ c2w,
        const float* __restrict__ fvec,
        float* __restrict__ om, unsigned short* __restrict__ w2b,
        unsigned short* __restrict__ fT) {
    __shared__ __align__(16) float smem[4416];
    int id = blockIdx.x, tid = threadIdx.x;
    if (id < 512)        conv_fast_body(id, tid, iT, wk2, com_b, om);
    else if (id < 1088)  w2_body(id - 512, tid, weight, c2w, fvec, w2b,
                                 smem, smem + 64*65);
    else                 transpose_body(input_feat, fT, id - 1088, tid, smem);
}

// K2-small: conv_lds (512) + w2 (576) + fT transpose (1024)
__global__ __launch_bounds__(256) void main2_small_kernel(
        const float* __restrict__ input_feat,
        const float* __restrict__ inter,
        const unsigned short* __restrict__ wk2,
        const float* __restrict__ com_b,
        const float* __restrict__ weight,
        const float* __restrict__ c2w,
        const float* __restrict__ fvec,
        float* __restrict__ om, unsigned short* __restrict__ w2b,
        unsigned short* __restrict__ fT) {
    __shared__ __align__(16) float smem[4416];
    int id = blockIdx.x, tid = threadIdx.x;
    if (id < 512)        conv_lds_body(id, tid, inter, wk2, com_b, om, smem);
    else if (id < 1088)  w2_body(id - 512, tid, weight, c2w, fvec, w2b,
                                 smem, smem + 64*65);
    else                 transpose_body(input_feat, fT, id - 1088, tid, smem);
}

// ---------------------------------------------------------------------------
// bilinear coord + gather-issue helper for dcn (kp is compile-time constant)
// ---------------------------------------------------------------------------
static __device__ __forceinline__ void bilin_issue(
        int y, int x, int kp, float oy, float ox, float omsk,
        const unsigned short* __restrict__ Fb, int qq,
        short8* dst, float* wdst) {
    float mv = 1.f / (1.f + expf(-omsk));
    float ysv = (float)(y - 1 + kp/3) + oy;
    float xsv = (float)(x - 1 + kp%3) + ox;
    float y0f = floorf(ysv), x0f = floorf(xsv);
    float ly = ysv - y0f, lx = xsv - x0f;
    int y0 = (int)y0f, x0i = (int)x0f;
    int y1 = y0 + 1, x1 = x0i + 1;
    float vy0 = (y0 >= 0 && y0 < HH) ? 1.f : 0.f;
    float vy1 = (y1 >= 0 && y1 < HH) ? 1.f : 0.f;
    float vx0 = (x0i >= 0 && x0i < WW) ? 1.f : 0.f;
    float vx1 = (x1 >= 0 && x1 < WW) ? 1.f : 0.f;
    wdst[0] = (1.f-ly)*(1.f-lx)*mv * vy0*vx0;
    wdst[1] = (1.f-ly)*lx      *mv * vy0*vx1;
    wdst[2] = ly      *(1.f-lx)*mv * vy1*vx0;
    wdst[3] = ly      *lx      *mv * vy1*vx1;
    int y0c = min(max(y0,0),HH-1), y1c = min(max(y1,0),HH-1);
    int x0c = min(max(x0i,0),WW-1), x1c = min(max(x1,0),WW-1);
    int i00 = y0c*WW + x0c, i01 = y0c*WW + x1c;
    int i10 = y1c*WW + x0c, i11 = y1c*WW + x1c;
    #pragma unroll
    for (int ks = 0; ks < 2; ++ks) {
        int co = ks*32 + qq*8;
        dst[ks*4+0] = *(const short8*)(Fb + (size_t)i00*64 + co);
        dst[ks*4+1] = *(const short8*)(Fb + (size_t)i01*64 + co);
        dst[ks*4+2] = *(const short8*)(Fb + (size_t)i10*64 + co);
        dst[ks*4+3] = *(const short8*)(Fb + (size_t)i11*64 + co);
    }
}

// ---------------------------------------------------------------------------
// K3: main DCN GEMM, bf16 MFMA, pipelined gathers PINNED by sched_barrier.
//     Segment order per p: [issue G(p+1)][load A(p)][pack(p)][MFMA(p)] | SB(0)
//     -> G(p+1) cannot sink past the barrier to its consumer (pack p+1),
//        so its 8 loads stay in flight across a full MFMA block.
// ---------------------------------------------------------------------------
__global__ __launch_bounds__(256, 4) void dcn_main_kernel(
        const unsigned short* __restrict__ fT,
        const unsigned short* __restrict__ w2b,
        const float* __restrict__ bias2,
        const float* __restrict__ om,
        float* __restrict__ out) {
    int b = blockIdx.z;
    int t = threadIdx.x;
    int lane = t & 63, wv = t >> 6;
    int nn = lane & 15, qq = lane >> 4;
    int px0 = blockIdx.x*64 + wv*16;
    int y = blockIdx.y;
    int x = px0 + nn;
    int pix = y*WW + x;
    const unsigned short* Fb = fT + (size_t)b*HW*64;
    const float* omb = om + (size_t)b*27*HW;
    const unsigned short* w2p = w2b + (size_t)(b*9)*4096;

    f32x4 acc[4];
    #pragma unroll
    for (int mt = 0; mt < 4; ++mt)
        #pragma unroll
        for (int j = 0; j < 4; ++j)
            acc[mt][j] = bias2[mt*16 + qq*4 + j];

    short8 cb[2][8];
    float  cw[2][4];

    // prologue: om p=0 -> issue gathers p=0; load om p=1
    float omy = omb[pix];
    float omx = omb[(size_t)HW + pix];
    float omm = omb[(size_t)18*HW + pix];
    bilin_issue(y, x, 0, omy, omx, omm, Fb, qq, cb[0], cw[0]);
    omy = omb[(size_t)2*HW + pix];
    omx = omb[(size_t)3*HW + pix];
    omm = omb[(size_t)19*HW + pix];

    #pragma unroll
    for (int p = 0; p < 9; ++p) {
        const int cur = p & 1, nxt = cur ^ 1;

        // issue gathers for p+1 (to overlap pack+MFMA of p)
        if (p < 8) {
            bilin_issue(y, x, p+1, omy, omx, omm, Fb, qq, cb[nxt], cw[nxt]);
            if (p < 7) {
                omy = omb[(size_t)(2*p+4)*HW + pix];
                omx = omb[(size_t)(2*p+5)*HW + pix];
                omm = omb[(size_t)(20+p )*HW + pix];
            }
        }

        // A-frags for p (L2-hot)
        short8 afr[4][2];
        #pragma unroll
        for (int mt = 0; mt < 4; ++mt)
            #pragma unroll
            for (int ks = 0; ks < 2; ++ks)
                afr[mt][ks] = *(const short8*)(w2p + (size_t)p*4096
                                + (size_t)(mt*16 + nn)*64 + ks*32 + qq*8);

        // pack p's corners (loads issued one iteration ago)
        short8 bfr[2];
        #pragma unroll
        for (int ks = 0; ks < 2; ++ks) {
            unsigned int pw[4];
            #pragma unroll
            for (int jp = 0; jp < 4; ++jp) {
                float v0 = cw[cur][0]*bf2f((unsigned short)cb[cur][ks*4+0][2*jp])
                         + cw[cur][1]*bf2f((unsigned short)cb[cur][ks*4+1][2*jp])
                         + cw[cur][2]*bf2f((unsigned short)cb[cur][ks*4+2][2*jp])
                         + cw[cur][3]*bf2f((unsigned short)cb[cur][ks*4+3][2*jp]);
                float v1 = cw[cur][0]*bf2f((unsigned short)cb[cur][ks*4+0][2*jp+1])
                         + cw[cur][1]*bf2f((unsigned short)cb[cur][ks*4+1][2*jp+1])
                         + cw[cur][2]*bf2f((unsigned short)cb[cur][ks*4+2][2*jp+1])
                         + cw[cur][3]*bf2f((unsigned short)cb[cur][ks*4+3][2*jp+1]);
                pw[jp] = (unsigned int)f2bf(v0) | ((unsigned int)f2bf(v1) << 16);
            }
            uint4v u4 = {pw[0], pw[1], pw[2], pw[3]};
            bfr[ks] = __builtin_bit_cast(short8, u4);
        }

        // MFMA
        #pragma unroll
        for (int ks = 0; ks < 2; ++ks)
            #pragma unroll
            for (int mt = 0; mt < 4; ++mt)
                acc[mt] = __builtin_amdgcn_mfma_f32_16x16x32_bf16(
                              afr[mt][ks], bfr[ks], acc[mt], 0, 0, 0);

        // pin: nothing crosses between p-iterations -> G(p+1) stays issued here
        __builtin_amdgcn_sched_barrier(0);
    }

    // epilogue: D[m=qq*4+j][n=nn]
    float* outp = out + (size_t)b*COUT*HW + (size_t)y*WW + px0 + nn;
    #pragma unroll
    for (int mt = 0; mt < 4; ++mt)
        #pragma unroll
        for (int j = 0; j < 4; ++j)
            outp[(size_t)(mt*16 + qq*4 + j)*HW] = acc[mt][j];
}

// ---------------------------------------------------------------------------
extern "C" void kernel_launch(void* const* d_in, const int* in_sizes, int n_in,
                              void* d_out, int out_size, void* d_ws, size_t ws_size,
                              hipStream_t stream) {
    const float* input_feat = (const float*)d_in[0];
    const float* inter      = (const float*)d_in[1];
    const float* fea        = (const float*)d_in[2];
    const float* weight     = (const float*)d_in[3];
    const float* bias       = (const float*)d_in[4];
    const float* com_w      = (const float*)d_in[5];
    const float* com_b      = (const float*)d_in[6];
    const float* c1w        = (const float*)d_in[7];
    const float* c2w        = (const float*)d_in[8];
    float* out = (float*)d_out;

    float* ws    = (float*)d_ws;
    float* fvec  = ws;                                     // 256
    float* bias2 = ws + 256;                               // 64 (pad to 512)
    unsigned short* w2b = (unsigned short*)(ws + 512);     // 147456 us
    float* om    = ws + 512 + 73728;                       // 1769472 f
    unsigned short* wk2 = (unsigned short*)(om + 1769472); // 20480 us
    unsigned short* fT  = wk2 + 20480;                     // 4194304 us
    unsigned short* iT  = fT + 4194304;                    // 4194304 us (big only)
    size_t need_big = ((size_t)(512 + 73728 + 1769472 + 10240 + 2097152 + 2097152))*4;
    bool big = ws_size >= need_big;

    if (big) {
        prep_big_kernel<<<1105, 256, 0, stream>>>(inter, c1w, fea, c2w, bias,
                com_w, iT, fvec, bias2, wk2);
        main2_big_kernel<<<2112, 256, 0, stream>>>(input_feat, iT, wk2, com_b,
                weight, c2w, fvec, om, w2b, fT);
    } else {
        prep_small_kernel<<<81, 256, 0, stream>>>(c1w, fea, c2w, bias, com_w,
                fvec, bias2, wk2);
        main2_small_kernel<<<2112, 256, 0, stream>>>(input_feat, inter, wk2,
                com_b, weight, c2w, fvec, om, w2b, fT);
    }
    dcn_main_kernel<<<dim3(2,128,4), 256, 0, stream>>>(fT, w2b, bias2, om, out);
}

// Round 11
// 192.816 us; speedup vs baseline: 1.0539x; 1.0539x over previous
//
#include <hip/hip_runtime.h>
#include <math.h>

// Problem constants
#define BB 4
#define CIN 64
#define COUT 64
#define HH 128
#define WW 128
#define HW (HH*WW)

typedef __attribute__((ext_vector_type(8))) short short8;   // 8 bf16 = 4 VGPRs
typedef __attribute__((ext_vector_type(4))) float f32x4;
typedef __attribute__((ext_vector_type(4))) unsigned int uint4v;

static __device__ __forceinline__ unsigned short f2bf(float f) {
    unsigned int u = __builtin_bit_cast(unsigned int, f);
    u += 0x7fffu + ((u >> 16) & 1u);          // round-to-nearest-even
    return (unsigned short)(u >> 16);
}
static __device__ __forceinline__ float bf2f(unsigned short h) {
    unsigned int u = ((unsigned int)h) << 16;
    return __builtin_bit_cast(float, u);
}

// ---------------------------------------------------------------------------
// K1: wkpack (80 blocks) + bias2 (1 block).  Tiny; everything else moved out.
// ---------------------------------------------------------------------------
__global__ __launch_bounds__(256) void prep_kernel(
        const float* __restrict__ com_w, const float* __restrict__ c2w,
        const float* __restrict__ bias,
        unsigned short* __restrict__ wk2, float* __restrict__ bias2) {
    int id = blockIdx.x, tid = threadIdx.x;
    if (id < 80) {
        int i = id*256 + tid;               // < 20480
        int k = i & 31, oc = (i >> 5) & 31;
        int cc5 = i >> 10;                  // cg*5 + chunk
        int cg = cc5 / 5, ch = cc5 % 5;
        int tap = ch*2 + (k >> 4);
        int c = cg*16 + (k & 15);
        float v = 0.f;
        if (tap < 9 && oc < 27) v = com_w[((size_t)oc*64 + c)*9 + tap];
        wk2[i] = f2bf(v);
    } else if (tid < COUT) {
        float s2 = 0.f;
        for (int o = 0; o < COUT; ++o) s2 += c2w[tid*COUT + o] * bias[o];
        bias2[tid] = s2;
    }
}

// ---------------------------------------------------------------------------
// channel-last bf16 transpose of one (b, 64-px strip): src[b][c][px]->dst[b][px][c]
// ---------------------------------------------------------------------------
static __device__ __forceinline__ void transpose_body(
        const float* __restrict__ srcb, unsigned short* __restrict__ dstb,
        int tb, int tid, float* lt /* 64*65 floats */) {
    int b = tb >> 8;
    int px0 = (tb & 255) * 64;
    const float* src = srcb + (size_t)b*CIN*HW + px0;
    for (int i = tid; i < 4096; i += 256) {
        int c = i >> 6, px = i & 63;
        lt[c*65 + px] = src[(size_t)c*HW + px];
    }
    __syncthreads();
    int q = tid & 3, px = tid >> 2;
    unsigned short* dst = dstb + ((size_t)b*HW + px0 + px)*64 + q*16;
    #pragma unroll
    for (int s = 0; s < 2; ++s) {
        short8 pk;
        #pragma unroll
        for (int j = 0; j < 8; ++j)
            pk[j] = (short)f2bf(lt[(q*16 + s*8 + j)*65 + px]);
        *(short8*)(dst + s*8) = pk;
    }
}

// ---------------------------------------------------------------------------
// w2 with INLINE fvec (wave-reduced): W2b[b][p][o2][c] bf16 (MFMA A layout)
// ---------------------------------------------------------------------------
static __device__ __forceinline__ void w2_body(
        int wid, int tid, const float* __restrict__ weight,
        const float* __restrict__ c2w, const float* __restrict__ c1w,
        const float* __restrict__ fea,
        unsigned short* __restrict__ w2b, float* c2s, float* wcol) {
    int o2 = tid & 63, ci = tid >> 6;
    int lane = tid & 63;
    int bp = wid >> 4;
    int c_base = (wid & 15)*4;
    int p = bp % 9, b = bp / 9;
    int c = c_base + ci;

    // inline fvec[b][c] for this wave's c: 4 MAC/lane + wave reduce
    float part = 0.f;
    #pragma unroll
    for (int s = 0; s < 4; ++s)
        part += c1w[c*(4*CIN) + lane + s*64] * fea[b*(4*CIN) + lane + s*64];
    #pragma unroll
    for (int off = 32; off; off >>= 1) part += __shfl_down(part, off);
    float fv = __shfl(part, 0);

    for (int idx = tid; idx < 4096; idx += 256) {
        int o2r = idx >> 6, oc = idx & 63;
        c2s[oc*65 + o2r] = c2w[idx];
    }
    {
        int o = tid & 63, cw = tid >> 6;
        wcol[cw*64 + o] = weight[(o*CIN + (c_base + cw))*9 + p];
    }
    __syncthreads();
    float s = 0.f;
    #pragma unroll 8
    for (int o = 0; o < COUT; ++o) s += c2s[o*65 + o2] * wcol[ci*64 + o];
    w2b[(size_t)bp*4096 + o2*64 + c] = f2bf(s * fv);
}

// ---------------------------------------------------------------------------
// conv via LDS im2col tile from fp32 inter (round-7-proven)
// ---------------------------------------------------------------------------
static __device__ __forceinline__ void conv_lds_body(
        int id, int tid, const float* __restrict__ inter,
        const unsigned short* __restrict__ wk2, const float* __restrict__ com_b,
        float* __restrict__ om, float* smemf) {
    unsigned short* til = (unsigned short*)smemf;   // [325][24]
    int bz = id >> 6;
    int b = bz >> 1, mh = bz & 1;
    int by = (id >> 3) & 7, bx = id & 7;
    int x0 = bx*16, y0 = by*16;
    int lane = tid & 63, wv = tid >> 6;
    int nn = lane & 15, qq = lane >> 4;

    f32x4 acc[4];
    #pragma unroll
    for (int nt = 0; nt < 4; ++nt)
        #pragma unroll
        for (int j = 0; j < 4; ++j) acc[nt][j] = 0.f;

    for (int cg = 0; cg < 4; ++cg) {
        __syncthreads();
        const float* I = inter + ((size_t)(b*CIN + cg*16))*HW;
        for (int i = tid; i < 16*324; i += 256) {
            int cl = i / 324, px = i % 324;
            int r = px / 18, cc = px % 18;
            int gy = y0 + r - 1, gx = x0 + cc - 1;
            float v = 0.f;
            if (gy >= 0 && gy < HH && gx >= 0 && gx < WW)
                v = I[(size_t)cl*HW + gy*WW + gx];
            til[px*24 + cl] = f2bf(v);
        }
        if (tid < 24) til[324*24 + tid] = 0;
        __syncthreads();

        short8 afr[5];
        #pragma unroll
        for (int ch = 0; ch < 5; ++ch)
            afr[ch] = *(const short8*)(wk2 +
                (((size_t)(cg*5 + ch)*32 + mh*16 + nn)*32 + qq*8));
        #pragma unroll
        for (int nt = 0; nt < 4; ++nt) {
            int row = wv*4 + nt;
            #pragma unroll
            for (int ch = 0; ch < 5; ++ch) {
                int tap = ch*2 + (qq >> 1);
                int px_idx;
                if (tap > 8) px_idx = 324;
                else {
                    int ky = tap/3, kx = tap%3;
                    px_idx = (row + ky)*18 + (nn + kx);
                }
                short8 bfr = *(const short8*)(til + px_idx*24 + (qq&1)*8);
                acc[nt] = __builtin_amdgcn_mfma_f32_16x16x32_bf16(
                              afr[ch], bfr, acc[nt], 0, 0, 0);
            }
        }
    }

    float* op = om + (size_t)b*27*HW;
    #pragma unroll
    for (int nt = 0; nt < 4; ++nt) {
        int pix = (y0 + wv*4 + nt)*WW + x0 + nn;
        #pragma unroll
        for (int j = 0; j < 4; ++j) {
            int oc = mh*16 + qq*4 + j;
            if (oc < 27)
                op[(size_t)oc*HW + pix] = acc[nt][j] + com_b[oc];
        }
    }
}

// ---------------------------------------------------------------------------
// K2: conv (512) + w2 (576) + fT transpose (1024) = 2112 blocks
// ---------------------------------------------------------------------------
__global__ __launch_bounds__(256) void main2_kernel(
        const float* __restrict__ input_feat,
        const float* __restrict__ inter,
        const unsigned short* __restrict__ wk2,
        const float* __restrict__ com_b,
        const float* __restrict__ weight,
        const float* __restrict__ c2w,
        const float* __restrict__ c1w,
        const float* __restrict__ fea,
        float* __restrict__ om, unsigned short* __restrict__ w2b,
        unsigned short* __restrict__ fT) {
    __shared__ __align__(16) float smem[4416];
    int id = blockIdx.x, tid = threadIdx.x;
    if (id < 512)        conv_lds_body(id, tid, inter, wk2, com_b, om, smem);
    else if (id < 1088)  w2_body(id - 512, tid, weight, c2w, c1w, fea, w2b,
                                 smem, smem + 64*65);
    else                 transpose_body(input_feat, fT, id - 1088, tid, smem);
}

// ---------------------------------------------------------------------------
// K3: main DCN GEMM, bf16 MFMA, SPLIT-K across wave pairs for 2x occupancy.
//     Wave pair (strip, kh): kh handles channels kh*32..kh*32+31 only ->
//     half the gather/A-load/MFMA chain per wave; partials combined via LDS
//     (one barrier).  Grid (4,128,4)=2048 blocks, 8 blocks/CU, 32 waves/CU.
// ---------------------------------------------------------------------------
__global__ __launch_bounds__(256) void dcn_main_kernel(
        const unsigned short* __restrict__ fT,
        const unsigned short* __restrict__ w2b,
        const float* __restrict__ bias2,
        const float* __restrict__ om,
        float* __restrict__ out) {
    __shared__ float red[16*2*64];   // [idx16][strip][lane] = 8 KB
    int b = blockIdx.z;
    int t = threadIdx.x;
    int lane = t & 63, wv = t >> 6;
    int strip = wv >> 1, kh = wv & 1;
    int nn = lane & 15, qq = lane >> 4;
    int px0 = blockIdx.x*32 + strip*16;
    int y = blockIdx.y;
    int x = px0 + nn;
    int pix = y*WW + x;
    const unsigned short* Fb = fT + (size_t)b*HW*64;
    const float* omb = om + (size_t)b*27*HW;
    const unsigned short* w2p = w2b + (size_t)(b*9)*4096 + kh*32 + qq*8;
    int co = kh*32 + qq*8;

    f32x4 acc[4];
    #pragma unroll
    for (int mt = 0; mt < 4; ++mt)
        #pragma unroll
        for (int j = 0; j < 4; ++j)
            acc[mt][j] = kh ? bias2[mt*16 + qq*4 + j] : 0.f;

    float omy = omb[pix];
    float omx = omb[(size_t)HW + pix];
    float omm = omb[(size_t)18*HW + pix];

    #pragma unroll
    for (int p = 0; p < 9; ++p) {
        // A-frags for my K-half (L2-hot)
        short8 afr[4];
        #pragma unroll
        for (int mt = 0; mt < 4; ++mt)
            afr[mt] = *(const short8*)(w2p + (size_t)p*4096 + (mt*16 + nn)*64);

        // bilinear corner weights for my pixel
        float mv = 1.f / (1.f + expf(-omm));
        float ysv = (float)(y - 1 + p/3) + omy;
        float xsv = (float)(x - 1 + p%3) + omx;
        float y0f = floorf(ysv), x0f = floorf(xsv);
        float ly = ysv - y0f, lx = xsv - x0f;
        int y0 = (int)y0f, x0i = (int)x0f;
        int y1 = y0 + 1, x1 = x0i + 1;
        float vy0 = (y0 >= 0 && y0 < HH) ? 1.f : 0.f;
        float vy1 = (y1 >= 0 && y1 < HH) ? 1.f : 0.f;
        float vx0 = (x0i >= 0 && x0i < WW) ? 1.f : 0.f;
        float vx1 = (x1 >= 0 && x1 < WW) ? 1.f : 0.f;
        float w00 = (1.f-ly)*(1.f-lx)*mv * vy0*vx0;
        float w01 = (1.f-ly)*lx      *mv * vy0*vx1;
        float w10 = ly      *(1.f-lx)*mv * vy1*vx0;
        float w11 = ly      *lx      *mv * vy1*vx1;
        int y0c = min(max(y0,0),HH-1), y1c = min(max(y1,0),HH-1);
        int x0c = min(max(x0i,0),WW-1), x1c = min(max(x1,0),WW-1);
        int i00 = y0c*WW + x0c, i01 = y0c*WW + x1c;
        int i10 = y1c*WW + x0c, i11 = y1c*WW + x1c;

        // prefetch next p's om
        if (p < 8) {
            omy = omb[(size_t)(2*p+2)*HW + pix];
            omx = omb[(size_t)(2*p+3)*HW + pix];
            omm = omb[(size_t)(19+p )*HW + pix];
        }

        // gather my 8 channels' 4 corners (16B each, channel-contiguous)
        short8 c00 = *(const short8*)(Fb + (size_t)i00*64 + co);
        short8 c01 = *(const short8*)(Fb + (size_t)i01*64 + co);
        short8 c10 = *(const short8*)(Fb + (size_t)i10*64 + co);
        short8 c11 = *(const short8*)(Fb + (size_t)i11*64 + co);

        // pack
        unsigned int pw[4];
        #pragma unroll
        for (int jp = 0; jp < 4; ++jp) {
            float v0 = w00*bf2f((unsigned short)c00[2*jp])
                     + w01*bf2f((unsigned short)c01[2*jp])
                     + w10*bf2f((unsigned short)c10[2*jp])
                     + w11*bf2f((unsigned short)c11[2*jp]);
            float v1 = w00*bf2f((unsigned short)c00[2*jp+1])
                     + w01*bf2f((unsigned short)c01[2*jp+1])
                     + w10*bf2f((unsigned short)c10[2*jp+1])
                     + w11*bf2f((unsigned short)c11[2*jp+1]);
            pw[jp] = (unsigned int)f2bf(v0) | ((unsigned int)f2bf(v1) << 16);
        }
        uint4v u4 = {pw[0], pw[1], pw[2], pw[3]};
        short8 bfr = __builtin_bit_cast(short8, u4);

        // MFMA (my K-half only)
        #pragma unroll
        for (int mt = 0; mt < 4; ++mt)
            acc[mt] = __builtin_amdgcn_mfma_f32_16x16x32_bf16(
                          afr[mt], bfr, acc[mt], 0, 0, 0);
    }

    // combine wave-pair partials via LDS (conflict-free: lane is fastest dim)
    if (kh == 0) {
        #pragma unroll
        for (int mt = 0; mt < 4; ++mt)
            #pragma unroll
            for (int j = 0; j < 4; ++j)
                red[(mt*4 + j)*128 + strip*64 + lane] = acc[mt][j];
    }
    __syncthreads();
    if (kh == 1) {
        float* outp = out + (size_t)b*COUT*HW + (size_t)y*WW + px0 + nn;
        #pragma unroll
        for (int mt = 0; mt < 4; ++mt)
            #pragma unroll
            for (int j = 0; j < 4; ++j)
                outp[(size_t)(mt*16 + qq*4 + j)*HW] =
                    acc[mt][j] + red[(mt*4 + j)*128 + strip*64 + lane];
    }
}

// ---------------------------------------------------------------------------
extern "C" void kernel_launch(void* const* d_in, const int* in_sizes, int n_in,
                              void* d_out, int out_size, void* d_ws, size_t ws_size,
                              hipStream_t stream) {
    const float* input_feat = (const float*)d_in[0];
    const float* inter      = (const float*)d_in[1];
    const float* fea        = (const float*)d_in[2];
    const float* weight     = (const float*)d_in[3];
    const float* bias       = (const float*)d_in[4];
    const float* com_w      = (const float*)d_in[5];
    const float* com_b      = (const float*)d_in[6];
    const float* c1w        = (const float*)d_in[7];
    const float* c2w        = (const float*)d_in[8];
    float* out = (float*)d_out;

    float* ws    = (float*)d_ws;
    float* bias2 = ws + 256;                               // 64 (in pad area)
    unsigned short* w2b = (unsigned short*)(ws + 512);     // 147456 us
    float* om    = ws + 512 + 73728;                       // 1769472 f
    unsigned short* wk2 = (unsigned short*)(om + 1769472); // 20480 us
    unsigned short* fT  = wk2 + 20480;                     // 4194304 us

    prep_kernel<<<81, 256, 0, stream>>>(com_w, c2w, bias, wk2, bias2);
    main2_kernel<<<2112, 256, 0, stream>>>(input_feat, inter, wk2, com_b,
                                           weight, c2w, c1w, fea, om, w2b, fT);
    dcn_main_kernel<<<dim3(4,128,4), 256, 0, stream>>>(fT, w2b, bias2, om, out);
}